// Round 18
// baseline (324.448 us; speedup 1.0000x reference)
//
#include <hip/hip_runtime.h>
#include <hip/hip_bf16.h>
#include <cstddef>

#define HW   50176
#define NPIX 100352
#define IW   224

typedef unsigned short ushort_t;
typedef __attribute__((ext_vector_type(8))) short bf16x8;
typedef __attribute__((ext_vector_type(8))) unsigned short ushort8;
typedef __attribute__((ext_vector_type(4))) float f32x4;
typedef __attribute__((ext_vector_type(2))) _Float16 f16x2;
typedef __attribute__((ext_vector_type(8))) _Float16 f16x8;

__device__ inline ushort_t f2bf(float f) {
    __hip_bfloat16 h = __float2bfloat16(f);
    return __builtin_bit_cast(ushort_t, h);
}
__device__ inline float bf2f(ushort_t u) {
    return __uint_as_float(((unsigned)u) << 16);
}
__device__ inline bf16x8 ldg8(const ushort_t* p) {
    return *reinterpret_cast<const bf16x8*>(p);
}
__device__ inline void b2f8(const ushort_t* p, float* f) {
    ushort8 v = *reinterpret_cast<const ushort8*>(p);
#pragma unroll
    for (int i = 0; i < 8; i++) f[i] = bf2f(v[i]);
}
__device__ inline f16x2 pk16(float a, float b) {
    return __builtin_bit_cast(f16x2, __builtin_amdgcn_cvt_pkrtz(a, b));
}

// async global->LDS DMA, 16 B per lane; lds dest must be wave-uniform.
__device__ inline void dma16(const ushort_t* g, ushort_t* l) {
    __builtin_amdgcn_global_load_lds(
        (const __attribute__((address_space(1))) void*)g,
        (__attribute__((address_space(3))) void*)l, 16, 0, 0);
}

// ---------------------------------------------------------------------------
// merged prep + conv1 kernel
// ---------------------------------------------------------------------------
__device__ void conv1_body(int gid, const float* __restrict__ x,
                           const float* __restrict__ w,
                           const float* __restrict__ bias,
                           ushort_t* __restrict__ out)
{
    int b = gid >= HW;
    int p = gid - b * HW;
    int y = p / IW, xx = p - y * IW;

    float v[27];
#pragma unroll
    for (int ci = 0; ci < 3; ci++) {
        const float* ip = x + ((size_t)(b * 3 + ci)) * HW;
#pragma unroll
        for (int t = 0; t < 9; t++) {
            int dy = t / 3 - 1, dx = t % 3 - 1;
            int yy = y + dy, xc = xx + dx;
            float tv = 0.f;
            if ((unsigned)yy < (unsigned)IW && (unsigned)xc < (unsigned)IW)
                tv = ip[yy * IW + xc];
            v[ci * 9 + t] = tv;
        }
    }
#pragma unroll
    for (int g = 0; g < 8; g++) {
        ushort8 o8;
#pragma unroll
        for (int i = 0; i < 8; i++) {
            int co = g * 8 + i;
            float a = bias[co];
            const float* wp = w + co * 27;
#pragma unroll
            for (int k = 0; k < 27; k++) a = fmaf(v[k], wp[k], a);
            o8[i] = f2bf(fmaxf(a, 0.f));
        }
        *reinterpret_cast<ushort8*>(out + (size_t)gid * 64 + g * 8) = o8;
    }
}

__global__ __launch_bounds__(256) void prep_conv1_k(
    const float* __restrict__ x,     const float* __restrict__ enc_w1,
    const float* __restrict__ enc_b1, ushort_t* __restrict__ E1b,
    const float* __restrict__ in_w,  ushort_t* __restrict__ in_wb,
    const float* __restrict__ out_w, ushort_t* __restrict__ out_wb,
    const float* __restrict__ w1,    ushort_t* __restrict__ w1p,
    const float* __restrict__ w2,    _Float16* __restrict__ w2s,
    const float* __restrict__ ec2,   ushort_t* __restrict__ wc2p,
    const float* __restrict__ s1,    ushort_t* __restrict__ ws1p,
    const float* __restrict__ s2,    ushort_t* __restrict__ ws2)
{
    if (blockIdx.x < 392) {
        conv1_body(blockIdx.x * 256 + threadIdx.x, x, enc_w1, enc_b1, E1b);
        return;
    }
    int idx = (blockIdx.x - 392) * 256 + threadIdx.x;
    if (idx < 12288) { in_wb[idx] = f2bf(in_w[idx]); return; }
    idx -= 12288;
    if (idx < 4096)  { out_wb[idx] = f2bf(out_w[idx]); return; }
    idx -= 4096;
    if (idx < 131072){
        int j = idx >> 6, e = idx & 63;
        int c = j >> 6, jl = j & 63;
        w1p[(size_t)c * 6144 + jl * 72 + e] = f2bf(w1[idx]);
        return;
    }
    idx -= 131072;
    if (idx < 131072){
        int j    = idx & 7;
        int lane = (idx >> 3) & 63;
        int rest = idx >> 9;          // (c*2+p)*4+nt
        int nt   = rest & 3;
        int cp   = rest >> 2;         // c*2+p
        int p    = cp & 1;
        int c    = cp >> 1;
        int quad = lane >> 4;
        int e2   = nt * 16 + (lane & 15);
        int hl   = (j < 4) ? (quad * 4 + j) : (16 + quad * 4 + (j - 4));
        int hidden = c * 64 + p * 32 + hl;
        w2s[idx] = (_Float16)w2[(size_t)e2 * 2048 + hidden];
        return;
    }
    idx -= 131072;
    if (idx < 36864) {
        int ci = idx & 63, co = (idx >> 6) & 63, t = idx >> 12;
        wc2p[(size_t)t * 4608 + co * 72 + ci] = f2bf(ec2[((size_t)co * 64 + ci) * 9 + t]);
        return;
    }
    idx -= 36864;
    if (idx < 18432) {
        int ci = idx & 63, co = (idx >> 6) & 31, t = idx >> 11;
        ws1p[(size_t)t * 2560 + co * 72 + ci] = f2bf(s1[((size_t)co * 64 + ci) * 9 + t]);
        return;
    }
    idx -= 18432;
    if (idx < 4608)  {
        int ci = idx % 32;
        int t  = (idx / 32) % 9;
        int co = idx / 288;
        ws2[idx] = (co < 9) ? f2bf(s2[((size_t)co * 32 + ci) * 9 + t]) : (ushort_t)0;
        return;
    }
}

// ---------------------------------------------------------------------------
// FUSED enc-conv2 + transformer front (R17 winner, unchanged).
// ---------------------------------------------------------------------------
__global__ __launch_bounds__(256) void enc2xf_k(
    const ushort_t* __restrict__ E1b, const ushort_t* __restrict__ Wc2p,
    const float* __restrict__ enc_b2,
    const ushort_t* __restrict__ Wqkv, const float* __restrict__ Bqkv,
    const ushort_t* __restrict__ Wo, const float* __restrict__ Bo,
    const float* __restrict__ g, const float* __restrict__ be,
    ushort_t* __restrict__ T1b)
{
    __shared__ ushort_t Q[128 * 200];   // 51.2 KB
    __shared__ ushort_t WT[9216];       // 18.4 KB: Wl[2][4608] then Tl[128*72]

    int tid = threadIdx.x, wave = tid >> 6, lane = tid & 63;
    int lm = lane & 15, quad = lane >> 4;
    int p0 = blockIdx.x * 64;

    // ---- phase 0: enc conv2 (64->64, 3x3) ----
    {
        int lr0 = wave * 32;
        int m[2], py[2], px[2];
#pragma unroll
        for (int mt = 0; mt < 2; mt++) {
            int lr = lr0 + mt * 16 + lm;
            int gp = p0 + (lr & 63);
            m[mt] = (lr >> 6) * HW + gp;
            py[mt] = gp / IW;
            px[mt] = gp - py[mt] * IW;
        }

        f32x4 acc[2][4] = {};
        bf16x8 zz = {};

        auto dma_tap = [&](int t, int pb) {
            const ushort_t* gw = Wc2p + (size_t)t * 4608;
#pragma unroll
            for (int i = 0; i < 3; i++) {
                int idx = i * 4 + wave;
                if (idx < 9)
                    dma16(gw + idx * 512 + lane * 8, &WT[pb * 4608 + idx * 512]);
            }
        };

        dma_tap(0, 0);

        for (int t = 0; t < 9; t++) {
            int pb = t & 1;
            __syncthreads();
            if (t < 8) dma_tap(t + 1, pb ^ 1);

            int dy = t / 3 - 1, dx = t % 3 - 1;
            bf16x8 af[2][2];
#pragma unroll
            for (int mt = 0; mt < 2; mt++) {
                bool ok = (unsigned)(py[mt] + dy) < (unsigned)IW &&
                          (unsigned)(px[mt] + dx) < (unsigned)IW;
                const ushort_t* ip = E1b + (size_t)(m[mt] + dy * IW + dx) * 64 + quad * 8;
#pragma unroll
                for (int ks = 0; ks < 2; ks++)
                    af[mt][ks] = ok ? ldg8(ip + ks * 32) : zz;
            }
#pragma unroll
            for (int nt = 0; nt < 4; nt++) {
                const ushort_t* wp = &WT[pb * 4608 + (nt * 16 + lm) * 72 + quad * 8];
#pragma unroll
                for (int ks = 0; ks < 2; ks++) {
                    bf16x8 bfv = *reinterpret_cast<const bf16x8*>(wp + ks * 32);
#pragma unroll
                    for (int mt = 0; mt < 2; mt++)
                        acc[mt][nt] = __builtin_amdgcn_mfma_f32_16x16x32_bf16(
                            af[mt][ks], bfv, acc[mt][nt], 0, 0, 0);
                }
            }
        }

        __syncthreads();   // everyone done reading Wl; WT becomes Tl
#pragma unroll
        for (int nt = 0; nt < 4; nt++) {
            float bv = enc_b2[nt * 16 + lm];
#pragma unroll
            for (int mt = 0; mt < 2; mt++)
#pragma unroll
                for (int r = 0; r < 4; r++) {
                    int lr = lr0 + mt * 16 + quad * 4 + r;
                    WT[lr * 72 + nt * 16 + lm] =
                        f2bf(fmaxf(acc[mt][nt][r] + bv, 0.f));
                }
        }
    }
    __syncthreads();

    // ---- phase A: qkv projection (input from Tl) into Q ----
#pragma unroll
    for (int mt = 0; mt < 2; mt++) {
        int lA = mt * 64 + wave * 16;
        bf16x8 a[2];
#pragma unroll
        for (int ks = 0; ks < 2; ks++)
            a[ks] = *reinterpret_cast<const bf16x8*>(
                &WT[(lA + lm) * 72 + ks * 32 + quad * 8]);
        f32x4 acc[12] = {};
#pragma unroll
        for (int nt = 0; nt < 12; nt++)
#pragma unroll
            for (int ks = 0; ks < 2; ks++) {
                bf16x8 b = ldg8(Wqkv + (size_t)(nt * 16 + lm) * 64 + ks * 32 + quad * 8);
                acc[nt] = __builtin_amdgcn_mfma_f32_16x16x32_bf16(a[ks], b, acc[nt], 0, 0, 0);
            }
        int lrow = lA + quad * 4;
#pragma unroll
        for (int nt = 0; nt < 12; nt++) {
            float bb = Bqkv[nt * 16 + lm];
#pragma unroll
            for (int r = 0; r < 4; r++)
                Q[(lrow + r) * 200 + nt * 16 + lm] = f2bf(acc[nt][r] + bb);
        }
    }
    __syncthreads();

    // ---- phase B: attention (per pixel x head, S=2) ----
    {
        int px = tid >> 2, h = tid & 3;
        ushort_t* r0 = &Q[px * 200 + h * 16];
        ushort_t* r1 = &Q[(64 + px) * 200 + h * 16];

        float q0[16], k0[16], v0[16], q1[16], k1[16], v1[16];
        b2f8(r0,       q0); b2f8(r0 + 8,   q0 + 8);
        b2f8(r0 + 64,  k0); b2f8(r0 + 72,  k0 + 8);
        b2f8(r0 + 128, v0); b2f8(r0 + 136, v0 + 8);
        b2f8(r1,       q1); b2f8(r1 + 8,   q1 + 8);
        b2f8(r1 + 64,  k1); b2f8(r1 + 72,  k1 + 8);
        b2f8(r1 + 128, v1); b2f8(r1 + 136, v1 + 8);

        float s00 = 0, s01 = 0, s10 = 0, s11 = 0;
#pragma unroll
        for (int d = 0; d < 16; d++) {
            s00 += q0[d] * k0[d]; s01 += q0[d] * k1[d];
            s10 += q1[d] * k0[d]; s11 += q1[d] * k1[d];
        }
        s00 *= 0.25f; s01 *= 0.25f; s10 *= 0.25f; s11 *= 0.25f;

        float m0 = fmaxf(s00, s01);
        float e00 = __expf(s00 - m0), e01 = __expf(s01 - m0);
        float i0 = 1.f / (e00 + e01);
        float p00 = e00 * i0, p01 = e01 * i0;

        float m1 = fmaxf(s10, s11);
        float e10 = __expf(s10 - m1), e11 = __expf(s11 - m1);
        float i1 = 1.f / (e10 + e11);
        float p10 = e10 * i1, p11 = e11 * i1;

#pragma unroll
        for (int c = 0; c < 2; c++) {
            ushort8 a0v, a1v;
#pragma unroll
            for (int i = 0; i < 8; i++) {
                int d = c * 8 + i;
                a0v[i] = f2bf(p00 * v0[d] + p01 * v1[d]);
                a1v[i] = f2bf(p10 * v0[d] + p11 * v1[d]);
            }
            *reinterpret_cast<ushort8*>(r0 + c * 8) = a0v;
            *reinterpret_cast<ushort8*>(r1 + c * 8) = a1v;
        }
    }
    __syncthreads();

    // ---- phase C: out-proj + residual(Tl) + LN1 -> t1 (global) ----
#pragma unroll
    for (int mt = 0; mt < 2; mt++) {
        int lA = mt * 64 + wave * 16;
        size_t gbase = (size_t)((mt == 0 ? p0 : HW + p0) + wave * 16);
        bf16x8 a[2];
#pragma unroll
        for (int ks = 0; ks < 2; ks++)
            a[ks] = *reinterpret_cast<const bf16x8*>(
                &Q[(lA + lm) * 200 + ks * 32 + quad * 8]);
        f32x4 acc[4] = {};
#pragma unroll
        for (int nt = 0; nt < 4; nt++)
#pragma unroll
            for (int ks = 0; ks < 2; ks++) {
                bf16x8 b = ldg8(Wo + (size_t)(nt * 16 + lm) * 64 + ks * 32 + quad * 8);
                acc[nt] = __builtin_amdgcn_mfma_f32_16x16x32_bf16(a[ks], b, acc[nt], 0, 0, 0);
            }

        float bv[4], gv[4], bev[4];
#pragma unroll
        for (int nt = 0; nt < 4; nt++) {
            bv[nt]  = Bo[nt * 16 + lm];
            gv[nt]  = g[nt * 16 + lm];
            bev[nt] = be[nt * 16 + lm];
        }
#pragma unroll
        for (int r = 0; r < 4; r++) {
            int lr = lA + quad * 4 + r;
            size_t row = gbase + quad * 4 + r;
            float v[4]; float s = 0.f;
#pragma unroll
            for (int nt = 0; nt < 4; nt++) {
                v[nt] = acc[nt][r] + bv[nt] + bf2f(WT[lr * 72 + nt * 16 + lm]);
                s += v[nt];
            }
#pragma unroll
            for (int o = 8; o; o >>= 1) s += __shfl_xor(s, o, 64);
            float mu = s * 0.015625f;
            float q = 0.f;
#pragma unroll
            for (int nt = 0; nt < 4; nt++) { v[nt] -= mu; q += v[nt] * v[nt]; }
#pragma unroll
            for (int o = 8; o; o >>= 1) q += __shfl_xor(q, o, 64);
            float rstd = rsqrtf(q * 0.015625f + 1e-5f);
#pragma unroll
            for (int nt = 0; nt < 4; nt++)
                T1b[row * 64 + nt * 16 + lm] = f2bf(gv[nt] * v[nt] * rstd + bev[nt]);
        }
    }
}

// ---------------------------------------------------------------------------
// NE-layout MFMA conv 3x3 with per-tap LDS-staged weights (sf1).
// ---------------------------------------------------------------------------
template<int KS, int NT, int TAPUS, int NISSUE, int ACT, bool WF32, bool WB16>
__global__ __launch_bounds__(256) void neconv_lds_k(
    const ushort_t* __restrict__ In, const ushort_t* __restrict__ Wp,
    const float* __restrict__ bias, float* __restrict__ Of,
    ushort_t* __restrict__ Ob)
{
    const int CIN = KS * 32, LDO = NT * 16;
    __shared__ ushort_t Wl[2][TAPUS];

    int tid = threadIdx.x, wave = tid >> 6, lane = tid & 63;
    int lm = lane & 15, quad = lane >> 4;
    int m0 = blockIdx.x * 128 + wave * 32;

    int m[2], py[2], px[2];
#pragma unroll
    for (int mt = 0; mt < 2; mt++) {
        int mm = m0 + mt * 16 + lm;
        m[mt] = mm;
        int p = mm - (mm >= HW ? HW : 0);
        py[mt] = p / IW;
        px[mt] = p - py[mt] * IW;
    }

    f32x4 acc[2][NT] = {};
    bf16x8 zz = {};

    auto dma_tap = [&](int t, int pb) {
        const ushort_t* g = Wp + (size_t)t * TAPUS;
#pragma unroll
        for (int i = 0; i < (NISSUE + 3) / 4; i++) {
            int idx = i * 4 + wave;
            if (idx < NISSUE)
                dma16(g + idx * 512 + lane * 8, &Wl[pb][idx * 512]);
        }
    };

    dma_tap(0, 0);

    for (int t = 0; t < 9; t++) {
        int pb = t & 1;
        __syncthreads();
        if (t < 8) dma_tap(t + 1, pb ^ 1);

        int dy = t / 3 - 1, dx = t % 3 - 1;
        bf16x8 af[2][KS];
#pragma unroll
        for (int mt = 0; mt < 2; mt++) {
            bool ok = (unsigned)(py[mt] + dy) < (unsigned)IW &&
                      (unsigned)(px[mt] + dx) < (unsigned)IW;
            const ushort_t* ip = In + (size_t)(m[mt] + dy * IW + dx) * CIN + quad * 8;
#pragma unroll
            for (int ks = 0; ks < KS; ks++)
                af[mt][ks] = ok ? ldg8(ip + ks * 32) : zz;
        }
#pragma unroll
        for (int nt = 0; nt < NT; nt++) {
            const ushort_t* wp = &Wl[pb][(nt * 16 + lm) * 72 + quad * 8];
#pragma unroll
            for (int ks = 0; ks < KS; ks++) {
                bf16x8 bfv = *reinterpret_cast<const bf16x8*>(wp + ks * 32);
#pragma unroll
                for (int mt = 0; mt < 2; mt++)
                    acc[mt][nt] = __builtin_amdgcn_mfma_f32_16x16x32_bf16(
                        af[mt][ks], bfv, acc[mt][nt], 0, 0, 0);
            }
        }
    }

#pragma unroll
    for (int nt = 0; nt < NT; nt++) {
        int col = nt * 16 + lm;
        float bv = bias[col];
#pragma unroll
        for (int mt = 0; mt < 2; mt++)
#pragma unroll
            for (int r = 0; r < 4; r++) {
                int row = m0 + mt * 16 + quad * 4 + r;
                float v = acc[mt][nt][r] + bv;
                if (ACT) v = fmaxf(v, 0.f);
                if (WF32) Of[(size_t)row * LDO + col] = v;
                if (WB16) Ob[(size_t)row * LDO + col] = f2bf(v);
            }
    }
}

// ---------------------------------------------------------------------------
// FFN v10: 784 blocks x 8 waves, mt=1 (16 rows/wave, 128 rows/block).
// Same LDS-shared weight staging as ffn8 but 2x grid concurrency
// (3.06 blocks/CU, ~24.5 waves/CU vs ffn8's 12.25).
// ---------------------------------------------------------------------------
__global__ __launch_bounds__(512) void ffn10_k(
    const ushort_t* __restrict__ T1b,
    const ushort_t* __restrict__ W1p, const float* __restrict__ B1,
    const _Float16* __restrict__ W2s, const float* __restrict__ B2,
    const float* __restrict__ g, const float* __restrict__ be,
    ushort_t* __restrict__ OutTb)
{
    __shared__ ushort_t W1lds[2][6144];
    __shared__ ushort_t W2lds[2][4096];

    int tid = threadIdx.x, wave = tid >> 6, lane = tid & 63;
    int lm = lane & 15, quad = lane >> 4;
    int rowbase = blockIdx.x * 128 + wave * 16;

    bf16x8 Bt[2];
#pragma unroll
    for (int ks = 0; ks < 2; ks++)
        Bt[ks] = ldg8(T1b + (size_t)(rowbase + lm) * 64 + ks * 32 + quad * 8);

    f32x4 acc[4] = {};

    auto dma_chunk = [&](int c, int pb) {
        const ushort_t* g1 = W1p + (size_t)c * 6144;
        const ushort_t* g2 = (const ushort_t*)(W2s + (size_t)c * 4096);
#pragma unroll
        for (int i = 0; i < 3; i++) {
            int idx = i * 8 + wave;
            if (idx < 12)
                dma16(g1 + idx * 512 + lane * 8, &W1lds[pb][idx * 512]);
            else if (idx < 20)
                dma16(g2 + (idx - 12) * 512 + lane * 8,
                      &W2lds[pb][(idx - 12) * 512]);
        }
    };

    dma_chunk(0, 0);

    for (int c = 0; c < 32; c++) {
        int pb = c & 1;
        __syncthreads();
        if (c + 1 < 32) dma_chunk(c + 1, pb ^ 1);

        const ushort_t* w1l = &W1lds[pb][0];
        const ushort_t* w2l = &W2lds[pb][0];

#pragma unroll
        for (int p = 0; p < 2; p++) {
            bf16x8 w1r[2][2];
            f16x8  w2r[4];
            float4 b1r[2];
#pragma unroll
            for (int s = 0; s < 2; s++) {
                int ul = p * 2 + s;
#pragma unroll
                for (int ks = 0; ks < 2; ks++)
                    w1r[s][ks] = *reinterpret_cast<const bf16x8*>(
                        &w1l[(ul * 16 + lm) * 72 + ks * 32 + quad * 8]);
                b1r[s] = *reinterpret_cast<const float4*>(B1 + (c * 4 + ul) * 16 + quad * 4);
            }
#pragma unroll
            for (int nt = 0; nt < 4; nt++)
                w2r[nt] = *reinterpret_cast<const f16x8*>(
                    &w2l[((p * 4 + nt) * 64 + lane) * 8]);

            // phase 1: bias-initialized accumulators (one row tile)
            f32x4 h[2];
#pragma unroll
            for (int s = 0; s < 2; s++) {
                f32x4 binit = {b1r[s].x, b1r[s].y, b1r[s].z, b1r[s].w};
                h[s] = binit;
            }
#pragma unroll
            for (int s = 0; s < 2; s++)
#pragma unroll
                for (int ks = 0; ks < 2; ks++)
                    h[s] = __builtin_amdgcn_mfma_f32_16x16x32_bf16(
                        w1r[s][ks], Bt[ks], h[s], 0, 0, 0);

            // relu + packed cvt -> paired-K A fragment
            f16x2 t0 = pk16(fmaxf(h[0][0], 0.f), fmaxf(h[0][1], 0.f));
            f16x2 t1 = pk16(fmaxf(h[0][2], 0.f), fmaxf(h[0][3], 0.f));
            f16x2 t2 = pk16(fmaxf(h[1][0], 0.f), fmaxf(h[1][1], 0.f));
            f16x2 t3 = pk16(fmaxf(h[1][2], 0.f), fmaxf(h[1][3], 0.f));
            f16x8 aH;
            aH[0] = t0[0]; aH[1] = t0[1]; aH[2] = t1[0]; aH[3] = t1[1];
            aH[4] = t2[0]; aH[5] = t2[1]; aH[6] = t3[0]; aH[7] = t3[1];

            // phase 2: paired-K f16 MFMA
#pragma unroll
            for (int nt = 0; nt < 4; nt++)
                acc[nt] = __builtin_amdgcn_mfma_f32_16x16x32_f16(
                    aH, w2r[nt], acc[nt], 0, 0, 0);
        }
    }

    // ---- epilogue: + b2 + residual(t1 bf16) -> LN2 -> bf16 ----
    float b2v[4], gv[4], bev[4];
#pragma unroll
    for (int nt = 0; nt < 4; nt++) {
        b2v[nt] = B2[nt * 16 + lm];
        gv[nt]  = g[nt * 16 + lm];
        bev[nt] = be[nt * 16 + lm];
    }
#pragma unroll
    for (int r = 0; r < 4; r++) {
        int row = rowbase + quad * 4 + r;
        float v[4]; float s = 0.f;
#pragma unroll
        for (int nt = 0; nt < 4; nt++) {
            v[nt] = acc[nt][r] + b2v[nt] +
                    bf2f(T1b[(size_t)row * 64 + nt * 16 + lm]);
            s += v[nt];
        }
#pragma unroll
        for (int o = 8; o; o >>= 1) s += __shfl_xor(s, o, 64);
        float mu = s * 0.015625f;
        float q = 0.f;
#pragma unroll
        for (int nt = 0; nt < 4; nt++) { v[nt] -= mu; q += v[nt] * v[nt]; }
#pragma unroll
        for (int o = 8; o; o >>= 1) q += __shfl_xor(q, o, 64);
        float rstd = rsqrtf(q * 0.015625f + 1e-5f);
#pragma unroll
        for (int nt = 0; nt < 4; nt++)
            OutTb[(size_t)row * 64 + nt * 16 + lm] =
                f2bf(gv[nt] * v[nt] * rstd + bev[nt]);
    }
}

// ---------------------------------------------------------------------------
// sf2 conv (32->9, MFMA) fused with KPN dynamic filtering.
// ---------------------------------------------------------------------------
__global__ __launch_bounds__(256) void sf2kpn_k(
    const ushort_t* __restrict__ In,
    const ushort_t* __restrict__ Wsw,
    const float* __restrict__ bias,
    const float* __restrict__ x,
    float* __restrict__ fused)
{
    __shared__ float Fl[128 * 12];
    int tid = threadIdx.x, wave = tid >> 6, lane = tid & 63;
    int lm = lane & 15, quad = lane >> 4;
    int m0 = blockIdx.x * 128 + wave * 32;

    int m[2], py[2], px[2];
#pragma unroll
    for (int mt = 0; mt < 2; mt++) {
        int mm = m0 + mt * 16 + lm;
        m[mt] = mm;
        int p = mm - (mm >= HW ? HW : 0);
        py[mt] = p / IW;
        px[mt] = p - py[mt] * IW;
    }

    f32x4 acc[2] = {};
    bf16x8 zz = {};

#pragma unroll 3
    for (int t = 0; t < 9; t++) {
        int dy = t / 3 - 1, dx = t % 3 - 1;
        bf16x8 af[2];
#pragma unroll
        for (int mt = 0; mt < 2; mt++) {
            bool ok = (unsigned)(py[mt] + dy) < (unsigned)IW &&
                      (unsigned)(px[mt] + dx) < (unsigned)IW;
            af[mt] = ok ? ldg8(In + (size_t)(m[mt] + dy * IW + dx) * 32 + quad * 8) : zz;
        }
        bf16x8 bfv = ldg8(Wsw + ((size_t)lm * 9 + t) * 32 + quad * 8);
#pragma unroll
        for (int mt = 0; mt < 2; mt++)
            acc[mt] = __builtin_amdgcn_mfma_f32_16x16x32_bf16(af[mt], bfv, acc[mt], 0, 0, 0);
    }

    if (lm < 9) {
        float bv = bias[lm];
#pragma unroll
        for (int mt = 0; mt < 2; mt++)
#pragma unroll
            for (int r = 0; r < 4; r++) {
                int lrow = wave * 32 + mt * 16 + quad * 4 + r;
                Fl[lrow * 12 + lm] = acc[mt][r] + bv;
            }
    }
    __syncthreads();

    if (tid < 128) {
        int gid = blockIdx.x * 128 + tid;
        int b = gid >= HW;
        int p = gid - b * HW;
        int y = p / IW, xx = p - y * IW;
        const float* fp = &Fl[tid * 12];
        const float* xp = x + (size_t)b * 3 * HW;
        float a = 0.f;
#pragma unroll
        for (int u = 0; u < 3; u++) {
            int yy = y + u - 1;
            if ((unsigned)yy >= (unsigned)IW) continue;
#pragma unroll
            for (int v = 0; v < 3; v++) {
                int xc = xx + v - 1;
                if ((unsigned)xc >= (unsigned)IW) continue;
                int o = yy * IW + xc;
                float s = xp[o] + xp[HW + o] + xp[2 * HW + o];
                a += fp[u * 3 + v] * s;
            }
        }
        fused[gid] = a;
    }
}

// ---------------------------------------------------------------------------
// fused decoder (1 thread/pixel — measured best)
// ---------------------------------------------------------------------------
__global__ __launch_bounds__(256) void dec_fused_k(
    const float* __restrict__ fused,
    const float* __restrict__ w1, const float* __restrict__ b1,
    const float* __restrict__ w2, const float* __restrict__ b2,
    float* __restrict__ out)
{
    int gid = blockIdx.x * 256 + threadIdx.x;
    int b = gid >= HW;
    int p = gid - b * HW;
    int y = p / IW, xx = p - y * IW;
    const float* ip = fused + (size_t)b * HW;

    float F[25];
#pragma unroll
    for (int u = 0; u < 5; u++)
#pragma unroll
        for (int v = 0; v < 5; v++) {
            int yy = y + u - 2, xc = xx + v - 2;
            float t = 0.f;
            if ((unsigned)yy < (unsigned)IW && (unsigned)xc < (unsigned)IW)
                t = ip[yy * IW + xc];
            F[u * 5 + v] = t;
        }
    float nm[9];
#pragma unroll
    for (int n = 0; n < 9; n++) {
        int yy = y + n / 3 - 1, xc = xx + n % 3 - 1;
        nm[n] = ((unsigned)yy < (unsigned)IW && (unsigned)xc < (unsigned)IW) ? 1.f : 0.f;
    }

    float acc = b2[0];
    for (int c = 0; c < 64; c++) {
        float w1c[9], w2c[9];
#pragma unroll
        for (int s = 0; s < 9; s++) { w1c[s] = w1[c * 9 + s]; w2c[s] = w2[c * 9 + s]; }
        float bc = b1[c];
#pragma unroll
        for (int n = 0; n < 9; n++) {
            int ny = n / 3, nx0 = n % 3;
            float h = bc;
#pragma unroll
            for (int s = 0; s < 9; s++)
                h = fmaf(F[(ny + s / 3) * 5 + (nx0 + s % 3)], w1c[s], h);
            acc = fmaf(fmaxf(h, 0.f), w2c[n] * nm[n], acc);
        }
    }
    out[gid] = 1.f / (1.f + __expf(-acc));
}

// ---------------------------------------------------------------------------
extern "C" void kernel_launch(void* const* d_in, const int* in_sizes, int n_in,
                              void* d_out, int out_size, void* d_ws, size_t ws_size,
                              hipStream_t stream)
{
    const float* x      = (const float*)d_in[0];
    const float* enc_w1 = (const float*)d_in[1];
    const float* enc_b1 = (const float*)d_in[2];
    const float* enc_w2 = (const float*)d_in[3];
    const float* enc_b2 = (const float*)d_in[4];
    const float* in_w   = (const float*)d_in[5];
    const float* in_b   = (const float*)d_in[6];
    const float* out_w  = (const float*)d_in[7];
    const float* out_b  = (const float*)d_in[8];
    const float* ln1_g  = (const float*)d_in[9];
    const float* ln1_b  = (const float*)d_in[10];
    const float* ffn_w1 = (const float*)d_in[11];
    const float* ffn_b1 = (const float*)d_in[12];
    const float* ffn_w2 = (const float*)d_in[13];
    const float* ffn_b2 = (const float*)d_in[14];
    const float* ln2_g  = (const float*)d_in[15];
    const float* ln2_b  = (const float*)d_in[16];
    const float* sf_w1  = (const float*)d_in[17];
    const float* sf_b1  = (const float*)d_in[18];
    const float* sf_w2  = (const float*)d_in[19];
    const float* sf_b2  = (const float*)d_in[20];
    const float* dec_w1 = (const float*)d_in[21];
    const float* dec_b1 = (const float*)d_in[22];
    const float* dec_w2 = (const float*)d_in[23];
    const float* dec_b2 = (const float*)d_in[24];

    float* ws = (float*)d_ws;
    const size_t SZ = (size_t)NPIX * 64;

    ushort_t* E1b  = (ushort_t*)(ws + 5 * SZ);             // conv1 out / t2 bf16
    ushort_t* Tb   = (ushort_t*)(ws + 11 * SZ / 2);        // t1 bf16
    ushort_t* wu   = (ushort_t*)(ws + 6 * SZ);             // weights
    ushort_t* in_wb  = wu;                                 // 12288
    ushort_t* out_wb = wu + 12288;                         // 4096
    ushort_t* w1p    = wu + 16384;                         // 196608 (padded chunks)
    _Float16* w2s    = (_Float16*)(wu + 212992);           // 131072 halves
    ushort_t* wc2p   = wu + 344064;                        // 41472 (tap-major padded)
    ushort_t* ws1p   = wu + 385536;                        // 23040 (tap-major padded)
    ushort_t* ws2    = wu + 408576;                        // 4608
    // late-stage scratch:
    float*    base3 = ws + 3 * SZ;
    ushort_t* s1b   = (ushort_t*)base3;                    // NPIX*32 bf16
    float*    fused = base3 + SZ / 2;                      // NPIX

    // ---- merged weight prep + conv1 ----
    prep_conv1_k<<<1714, 256, 0, stream>>>(
        x, enc_w1, enc_b1, E1b,
        in_w, in_wb, out_w, out_wb, ffn_w1, w1p,
        ffn_w2, w2s, enc_w2, wc2p, sf_w1, ws1p, sf_w2, ws2);

    // ---- fused enc-conv2 + transformer front -> t1 (Tb) ----
    enc2xf_k<<<784, 256, 0, stream>>>(E1b, wc2p, enc_b2,
                                      in_wb, in_b, out_wb, out_b,
                                      ln1_g, ln1_b, Tb);
    // ---- FFN (+res+LN2) -> t2 (E1b, dead after enc2xf) ----
    ffn10_k<<<784, 512, 0, stream>>>(Tb, w1p, ffn_b1, w2s, ffn_b2, ln2_g, ln2_b, E1b);
    // ---- filter prediction ----
    neconv_lds_k<2, 2, 2560, 5, 0, false, true><<<784, 256, 0, stream>>>(
        E1b, ws1p, sf_b1, nullptr, s1b);
    // ---- sf2 conv + KPN fused ----
    sf2kpn_k<<<784, 256, 0, stream>>>(s1b, ws2, sf_b2, x, fused);
    // ---- fused decoder ----
    dec_fused_k<<<392, 256, 0, stream>>>(fused, dec_w1, dec_b1, dec_w2, dec_b2,
                                         (float*)d_out);
}

// Round 19
// 312.629 us; speedup vs baseline: 1.0378x; 1.0378x over previous
//
#include <hip/hip_runtime.h>
#include <hip/hip_bf16.h>
#include <cstddef>

#define HW   50176
#define NPIX 100352
#define IW   224

typedef unsigned short ushort_t;
typedef __attribute__((ext_vector_type(8))) short bf16x8;
typedef __attribute__((ext_vector_type(8))) unsigned short ushort8;
typedef __attribute__((ext_vector_type(4))) float f32x4;
typedef __attribute__((ext_vector_type(2))) _Float16 f16x2;
typedef __attribute__((ext_vector_type(8))) _Float16 f16x8;

__device__ inline ushort_t f2bf(float f) {
    __hip_bfloat16 h = __float2bfloat16(f);
    return __builtin_bit_cast(ushort_t, h);
}
__device__ inline float bf2f(ushort_t u) {
    return __uint_as_float(((unsigned)u) << 16);
}
__device__ inline bf16x8 ldg8(const ushort_t* p) {
    return *reinterpret_cast<const bf16x8*>(p);
}
__device__ inline void b2f8(const ushort_t* p, float* f) {
    ushort8 v = *reinterpret_cast<const ushort8*>(p);
#pragma unroll
    for (int i = 0; i < 8; i++) f[i] = bf2f(v[i]);
}
__device__ inline f16x2 pk16(float a, float b) {
    return __builtin_bit_cast(f16x2, __builtin_amdgcn_cvt_pkrtz(a, b));
}

// async global->LDS DMA, 16 B per lane; lds dest must be wave-uniform.
__device__ inline void dma16(const ushort_t* g, ushort_t* l) {
    __builtin_amdgcn_global_load_lds(
        (const __attribute__((address_space(1))) void*)g,
        (__attribute__((address_space(3))) void*)l, 16, 0, 0);
}

// ---------------------------------------------------------------------------
// merged prep + conv1 kernel
// ---------------------------------------------------------------------------
__device__ void conv1_body(int gid, const float* __restrict__ x,
                           const float* __restrict__ w,
                           const float* __restrict__ bias,
                           ushort_t* __restrict__ out)
{
    int b = gid >= HW;
    int p = gid - b * HW;
    int y = p / IW, xx = p - y * IW;

    float v[27];
#pragma unroll
    for (int ci = 0; ci < 3; ci++) {
        const float* ip = x + ((size_t)(b * 3 + ci)) * HW;
#pragma unroll
        for (int t = 0; t < 9; t++) {
            int dy = t / 3 - 1, dx = t % 3 - 1;
            int yy = y + dy, xc = xx + dx;
            float tv = 0.f;
            if ((unsigned)yy < (unsigned)IW && (unsigned)xc < (unsigned)IW)
                tv = ip[yy * IW + xc];
            v[ci * 9 + t] = tv;
        }
    }
#pragma unroll
    for (int g = 0; g < 8; g++) {
        ushort8 o8;
#pragma unroll
        for (int i = 0; i < 8; i++) {
            int co = g * 8 + i;
            float a = bias[co];
            const float* wp = w + co * 27;
#pragma unroll
            for (int k = 0; k < 27; k++) a = fmaf(v[k], wp[k], a);
            o8[i] = f2bf(fmaxf(a, 0.f));
        }
        *reinterpret_cast<ushort8*>(out + (size_t)gid * 64 + g * 8) = o8;
    }
}

__global__ __launch_bounds__(256) void prep_conv1_k(
    const float* __restrict__ x,     const float* __restrict__ enc_w1,
    const float* __restrict__ enc_b1, ushort_t* __restrict__ E1b,
    const float* __restrict__ in_w,  ushort_t* __restrict__ in_wb,
    const float* __restrict__ out_w, ushort_t* __restrict__ out_wb,
    const float* __restrict__ w1,    ushort_t* __restrict__ w1p,
    const float* __restrict__ w2,    _Float16* __restrict__ w2s,
    const float* __restrict__ ec2,   ushort_t* __restrict__ wc2p,
    const float* __restrict__ s1,    ushort_t* __restrict__ ws1p,
    const float* __restrict__ s2,    ushort_t* __restrict__ ws2)
{
    if (blockIdx.x < 392) {
        conv1_body(blockIdx.x * 256 + threadIdx.x, x, enc_w1, enc_b1, E1b);
        return;
    }
    int idx = (blockIdx.x - 392) * 256 + threadIdx.x;
    if (idx < 12288) { in_wb[idx] = f2bf(in_w[idx]); return; }
    idx -= 12288;
    if (idx < 4096)  { out_wb[idx] = f2bf(out_w[idx]); return; }
    idx -= 4096;
    if (idx < 131072){
        int j = idx >> 6, e = idx & 63;
        int c = j >> 6, jl = j & 63;
        w1p[(size_t)c * 6144 + jl * 72 + e] = f2bf(w1[idx]);
        return;
    }
    idx -= 131072;
    if (idx < 131072){
        int j    = idx & 7;
        int lane = (idx >> 3) & 63;
        int rest = idx >> 9;          // (c*2+p)*4+nt
        int nt   = rest & 3;
        int cp   = rest >> 2;         // c*2+p
        int p    = cp & 1;
        int c    = cp >> 1;
        int quad = lane >> 4;
        int e2   = nt * 16 + (lane & 15);
        int hl   = (j < 4) ? (quad * 4 + j) : (16 + quad * 4 + (j - 4));
        int hidden = c * 64 + p * 32 + hl;
        w2s[idx] = (_Float16)w2[(size_t)e2 * 2048 + hidden];
        return;
    }
    idx -= 131072;
    if (idx < 36864) {
        int ci = idx & 63, co = (idx >> 6) & 63, t = idx >> 12;
        wc2p[(size_t)t * 4608 + co * 72 + ci] = f2bf(ec2[((size_t)co * 64 + ci) * 9 + t]);
        return;
    }
    idx -= 36864;
    if (idx < 18432) {
        int ci = idx & 63, co = (idx >> 6) & 31, t = idx >> 11;
        ws1p[(size_t)t * 2560 + co * 72 + ci] = f2bf(s1[((size_t)co * 64 + ci) * 9 + t]);
        return;
    }
    idx -= 18432;
    if (idx < 4608)  {
        int ci = idx % 32;
        int t  = (idx / 32) % 9;
        int co = idx / 288;
        ws2[idx] = (co < 9) ? f2bf(s2[((size_t)co * 32 + ci) * 9 + t]) : (ushort_t)0;
        return;
    }
}

// ---------------------------------------------------------------------------
// FUSED enc-conv2 + transformer front (R17 winner).
// ---------------------------------------------------------------------------
__global__ __launch_bounds__(256) void enc2xf_k(
    const ushort_t* __restrict__ E1b, const ushort_t* __restrict__ Wc2p,
    const float* __restrict__ enc_b2,
    const ushort_t* __restrict__ Wqkv, const float* __restrict__ Bqkv,
    const ushort_t* __restrict__ Wo, const float* __restrict__ Bo,
    const float* __restrict__ g, const float* __restrict__ be,
    ushort_t* __restrict__ T1b)
{
    __shared__ ushort_t Q[128 * 200];   // 51.2 KB
    __shared__ ushort_t WT[9216];       // 18.4 KB: Wl[2][4608] then Tl[128*72]

    int tid = threadIdx.x, wave = tid >> 6, lane = tid & 63;
    int lm = lane & 15, quad = lane >> 4;
    int p0 = blockIdx.x * 64;

    // ---- phase 0: enc conv2 (64->64, 3x3) ----
    {
        int lr0 = wave * 32;
        int m[2], py[2], px[2];
#pragma unroll
        for (int mt = 0; mt < 2; mt++) {
            int lr = lr0 + mt * 16 + lm;
            int gp = p0 + (lr & 63);
            m[mt] = (lr >> 6) * HW + gp;
            py[mt] = gp / IW;
            px[mt] = gp - py[mt] * IW;
        }

        f32x4 acc[2][4] = {};
        bf16x8 zz = {};

        auto dma_tap = [&](int t, int pb) {
            const ushort_t* gw = Wc2p + (size_t)t * 4608;
#pragma unroll
            for (int i = 0; i < 3; i++) {
                int idx = i * 4 + wave;
                if (idx < 9)
                    dma16(gw + idx * 512 + lane * 8, &WT[pb * 4608 + idx * 512]);
            }
        };

        dma_tap(0, 0);

        for (int t = 0; t < 9; t++) {
            int pb = t & 1;
            __syncthreads();
            if (t < 8) dma_tap(t + 1, pb ^ 1);

            int dy = t / 3 - 1, dx = t % 3 - 1;
            bf16x8 af[2][2];
#pragma unroll
            for (int mt = 0; mt < 2; mt++) {
                bool ok = (unsigned)(py[mt] + dy) < (unsigned)IW &&
                          (unsigned)(px[mt] + dx) < (unsigned)IW;
                const ushort_t* ip = E1b + (size_t)(m[mt] + dy * IW + dx) * 64 + quad * 8;
#pragma unroll
                for (int ks = 0; ks < 2; ks++)
                    af[mt][ks] = ok ? ldg8(ip + ks * 32) : zz;
            }
#pragma unroll
            for (int nt = 0; nt < 4; nt++) {
                const ushort_t* wp = &WT[pb * 4608 + (nt * 16 + lm) * 72 + quad * 8];
#pragma unroll
                for (int ks = 0; ks < 2; ks++) {
                    bf16x8 bfv = *reinterpret_cast<const bf16x8*>(wp + ks * 32);
#pragma unroll
                    for (int mt = 0; mt < 2; mt++)
                        acc[mt][nt] = __builtin_amdgcn_mfma_f32_16x16x32_bf16(
                            af[mt][ks], bfv, acc[mt][nt], 0, 0, 0);
                }
            }
        }

        __syncthreads();   // everyone done reading Wl; WT becomes Tl
#pragma unroll
        for (int nt = 0; nt < 4; nt++) {
            float bv = enc_b2[nt * 16 + lm];
#pragma unroll
            for (int mt = 0; mt < 2; mt++)
#pragma unroll
                for (int r = 0; r < 4; r++) {
                    int lr = lr0 + mt * 16 + quad * 4 + r;
                    WT[lr * 72 + nt * 16 + lm] =
                        f2bf(fmaxf(acc[mt][nt][r] + bv, 0.f));
                }
        }
    }
    __syncthreads();

    // ---- phase A: qkv projection (input from Tl) into Q ----
#pragma unroll
    for (int mt = 0; mt < 2; mt++) {
        int lA = mt * 64 + wave * 16;
        bf16x8 a[2];
#pragma unroll
        for (int ks = 0; ks < 2; ks++)
            a[ks] = *reinterpret_cast<const bf16x8*>(
                &WT[(lA + lm) * 72 + ks * 32 + quad * 8]);
        f32x4 acc[12] = {};
#pragma unroll
        for (int nt = 0; nt < 12; nt++)
#pragma unroll
            for (int ks = 0; ks < 2; ks++) {
                bf16x8 b = ldg8(Wqkv + (size_t)(nt * 16 + lm) * 64 + ks * 32 + quad * 8);
                acc[nt] = __builtin_amdgcn_mfma_f32_16x16x32_bf16(a[ks], b, acc[nt], 0, 0, 0);
            }
        int lrow = lA + quad * 4;
#pragma unroll
        for (int nt = 0; nt < 12; nt++) {
            float bb = Bqkv[nt * 16 + lm];
#pragma unroll
            for (int r = 0; r < 4; r++)
                Q[(lrow + r) * 200 + nt * 16 + lm] = f2bf(acc[nt][r] + bb);
        }
    }
    __syncthreads();

    // ---- phase B: attention (per pixel x head, S=2) ----
    {
        int px = tid >> 2, h = tid & 3;
        ushort_t* r0 = &Q[px * 200 + h * 16];
        ushort_t* r1 = &Q[(64 + px) * 200 + h * 16];

        float q0[16], k0[16], v0[16], q1[16], k1[16], v1[16];
        b2f8(r0,       q0); b2f8(r0 + 8,   q0 + 8);
        b2f8(r0 + 64,  k0); b2f8(r0 + 72,  k0 + 8);
        b2f8(r0 + 128, v0); b2f8(r0 + 136, v0 + 8);
        b2f8(r1,       q1); b2f8(r1 + 8,   q1 + 8);
        b2f8(r1 + 64,  k1); b2f8(r1 + 72,  k1 + 8);
        b2f8(r1 + 128, v1); b2f8(r1 + 136, v1 + 8);

        float s00 = 0, s01 = 0, s10 = 0, s11 = 0;
#pragma unroll
        for (int d = 0; d < 16; d++) {
            s00 += q0[d] * k0[d]; s01 += q0[d] * k1[d];
            s10 += q1[d] * k0[d]; s11 += q1[d] * k1[d];
        }
        s00 *= 0.25f; s01 *= 0.25f; s10 *= 0.25f; s11 *= 0.25f;

        float m0 = fmaxf(s00, s01);
        float e00 = __expf(s00 - m0), e01 = __expf(s01 - m0);
        float i0 = 1.f / (e00 + e01);
        float p00 = e00 * i0, p01 = e01 * i0;

        float m1 = fmaxf(s10, s11);
        float e10 = __expf(s10 - m1), e11 = __expf(s11 - m1);
        float i1 = 1.f / (e10 + e11);
        float p10 = e10 * i1, p11 = e11 * i1;

#pragma unroll
        for (int c = 0; c < 2; c++) {
            ushort8 a0v, a1v;
#pragma unroll
            for (int i = 0; i < 8; i++) {
                int d = c * 8 + i;
                a0v[i] = f2bf(p00 * v0[d] + p01 * v1[d]);
                a1v[i] = f2bf(p10 * v0[d] + p11 * v1[d]);
            }
            *reinterpret_cast<ushort8*>(r0 + c * 8) = a0v;
            *reinterpret_cast<ushort8*>(r1 + c * 8) = a1v;
        }
    }
    __syncthreads();

    // ---- phase C: out-proj + residual(Tl) + LN1 -> t1 (global) ----
#pragma unroll
    for (int mt = 0; mt < 2; mt++) {
        int lA = mt * 64 + wave * 16;
        size_t gbase = (size_t)((mt == 0 ? p0 : HW + p0) + wave * 16);
        bf16x8 a[2];
#pragma unroll
        for (int ks = 0; ks < 2; ks++)
            a[ks] = *reinterpret_cast<const bf16x8*>(
                &Q[(lA + lm) * 200 + ks * 32 + quad * 8]);
        f32x4 acc[4] = {};
#pragma unroll
        for (int nt = 0; nt < 4; nt++)
#pragma unroll
            for (int ks = 0; ks < 2; ks++) {
                bf16x8 b = ldg8(Wo + (size_t)(nt * 16 + lm) * 64 + ks * 32 + quad * 8);
                acc[nt] = __builtin_amdgcn_mfma_f32_16x16x32_bf16(a[ks], b, acc[nt], 0, 0, 0);
            }

        float bv[4], gv[4], bev[4];
#pragma unroll
        for (int nt = 0; nt < 4; nt++) {
            bv[nt]  = Bo[nt * 16 + lm];
            gv[nt]  = g[nt * 16 + lm];
            bev[nt] = be[nt * 16 + lm];
        }
#pragma unroll
        for (int r = 0; r < 4; r++) {
            int lr = lA + quad * 4 + r;
            size_t row = gbase + quad * 4 + r;
            float v[4]; float s = 0.f;
#pragma unroll
            for (int nt = 0; nt < 4; nt++) {
                v[nt] = acc[nt][r] + bv[nt] + bf2f(WT[lr * 72 + nt * 16 + lm]);
                s += v[nt];
            }
#pragma unroll
            for (int o = 8; o; o >>= 1) s += __shfl_xor(s, o, 64);
            float mu = s * 0.015625f;
            float q = 0.f;
#pragma unroll
            for (int nt = 0; nt < 4; nt++) { v[nt] -= mu; q += v[nt] * v[nt]; }
#pragma unroll
            for (int o = 8; o; o >>= 1) q += __shfl_xor(q, o, 64);
            float rstd = rsqrtf(q * 0.015625f + 1e-5f);
#pragma unroll
            for (int nt = 0; nt < 4; nt++)
                T1b[row * 64 + nt * 16 + lm] = f2bf(gv[nt] * v[nt] * rstd + bev[nt]);
        }
    }
}

// ---------------------------------------------------------------------------
// NE-layout MFMA conv 3x3 with per-tap LDS-staged weights (sf1).
// ---------------------------------------------------------------------------
template<int KS, int NT, int TAPUS, int NISSUE, int ACT, bool WF32, bool WB16>
__global__ __launch_bounds__(256) void neconv_lds_k(
    const ushort_t* __restrict__ In, const ushort_t* __restrict__ Wp,
    const float* __restrict__ bias, float* __restrict__ Of,
    ushort_t* __restrict__ Ob)
{
    const int CIN = KS * 32, LDO = NT * 16;
    __shared__ ushort_t Wl[2][TAPUS];

    int tid = threadIdx.x, wave = tid >> 6, lane = tid & 63;
    int lm = lane & 15, quad = lane >> 4;
    int m0 = blockIdx.x * 128 + wave * 32;

    int m[2], py[2], px[2];
#pragma unroll
    for (int mt = 0; mt < 2; mt++) {
        int mm = m0 + mt * 16 + lm;
        m[mt] = mm;
        int p = mm - (mm >= HW ? HW : 0);
        py[mt] = p / IW;
        px[mt] = p - py[mt] * IW;
    }

    f32x4 acc[2][NT] = {};
    bf16x8 zz = {};

    auto dma_tap = [&](int t, int pb) {
        const ushort_t* g = Wp + (size_t)t * TAPUS;
#pragma unroll
        for (int i = 0; i < (NISSUE + 3) / 4; i++) {
            int idx = i * 4 + wave;
            if (idx < NISSUE)
                dma16(g + idx * 512 + lane * 8, &Wl[pb][idx * 512]);
        }
    };

    dma_tap(0, 0);

    for (int t = 0; t < 9; t++) {
        int pb = t & 1;
        __syncthreads();
        if (t < 8) dma_tap(t + 1, pb ^ 1);

        int dy = t / 3 - 1, dx = t % 3 - 1;
        bf16x8 af[2][KS];
#pragma unroll
        for (int mt = 0; mt < 2; mt++) {
            bool ok = (unsigned)(py[mt] + dy) < (unsigned)IW &&
                      (unsigned)(px[mt] + dx) < (unsigned)IW;
            const ushort_t* ip = In + (size_t)(m[mt] + dy * IW + dx) * CIN + quad * 8;
#pragma unroll
            for (int ks = 0; ks < KS; ks++)
                af[mt][ks] = ok ? ldg8(ip + ks * 32) : zz;
        }
#pragma unroll
        for (int nt = 0; nt < NT; nt++) {
            const ushort_t* wp = &Wl[pb][(nt * 16 + lm) * 72 + quad * 8];
#pragma unroll
            for (int ks = 0; ks < KS; ks++) {
                bf16x8 bfv = *reinterpret_cast<const bf16x8*>(wp + ks * 32);
#pragma unroll
                for (int mt = 0; mt < 2; mt++)
                    acc[mt][nt] = __builtin_amdgcn_mfma_f32_16x16x32_bf16(
                        af[mt][ks], bfv, acc[mt][nt], 0, 0, 0);
            }
        }
    }

#pragma unroll
    for (int nt = 0; nt < NT; nt++) {
        int col = nt * 16 + lm;
        float bv = bias[col];
#pragma unroll
        for (int mt = 0; mt < 2; mt++)
#pragma unroll
            for (int r = 0; r < 4; r++) {
                int row = m0 + mt * 16 + quad * 4 + r;
                float v = acc[mt][nt][r] + bv;
                if (ACT) v = fmaxf(v, 0.f);
                if (WF32) Of[(size_t)row * LDO + col] = v;
                if (WB16) Ob[(size_t)row * LDO + col] = f2bf(v);
            }
    }
}

// ---------------------------------------------------------------------------
// FFN v8 (measured best of the family: 392x512, 8 waves share chunk, mt=2).
// ---------------------------------------------------------------------------
__global__ __launch_bounds__(512) void ffn8_k(
    const ushort_t* __restrict__ T1b,
    const ushort_t* __restrict__ W1p, const float* __restrict__ B1,
    const _Float16* __restrict__ W2s, const float* __restrict__ B2,
    const float* __restrict__ g, const float* __restrict__ be,
    ushort_t* __restrict__ OutTb)
{
    __shared__ ushort_t W1lds[2][6144];
    __shared__ ushort_t W2lds[2][4096];

    int tid = threadIdx.x, wave = tid >> 6, lane = tid & 63;
    int lm = lane & 15, quad = lane >> 4;
    int rowbase = blockIdx.x * 256 + wave * 32;

    bf16x8 Bt[2][2];
#pragma unroll
    for (int mt = 0; mt < 2; mt++)
#pragma unroll
        for (int ks = 0; ks < 2; ks++)
            Bt[mt][ks] = ldg8(T1b + (size_t)(rowbase + mt * 16 + lm) * 64 + ks * 32 + quad * 8);

    f32x4 acc[2][4] = {};

    auto dma_chunk = [&](int c, int pb) {
        const ushort_t* g1 = W1p + (size_t)c * 6144;
        const ushort_t* g2 = (const ushort_t*)(W2s + (size_t)c * 4096);
#pragma unroll
        for (int i = 0; i < 3; i++) {
            int idx = i * 8 + wave;
            if (idx < 12)
                dma16(g1 + idx * 512 + lane * 8, &W1lds[pb][idx * 512]);
            else if (idx < 20)
                dma16(g2 + (idx - 12) * 512 + lane * 8,
                      &W2lds[pb][(idx - 12) * 512]);
        }
    };

    dma_chunk(0, 0);

    for (int c = 0; c < 32; c++) {
        int pb = c & 1;
        __syncthreads();
        if (c + 1 < 32) dma_chunk(c + 1, pb ^ 1);

        const ushort_t* w1l = &W1lds[pb][0];
        const ushort_t* w2l = &W2lds[pb][0];

#pragma unroll
        for (int p = 0; p < 2; p++) {
            bf16x8 w1r[2][2];
            f16x8  w2r[4];
            float4 b1r[2];
#pragma unroll
            for (int s = 0; s < 2; s++) {
                int ul = p * 2 + s;
#pragma unroll
                for (int ks = 0; ks < 2; ks++)
                    w1r[s][ks] = *reinterpret_cast<const bf16x8*>(
                        &w1l[(ul * 16 + lm) * 72 + ks * 32 + quad * 8]);
                b1r[s] = *reinterpret_cast<const float4*>(B1 + (c * 4 + ul) * 16 + quad * 4);
            }
#pragma unroll
            for (int nt = 0; nt < 4; nt++)
                w2r[nt] = *reinterpret_cast<const f16x8*>(
                    &w2l[((p * 4 + nt) * 64 + lane) * 8]);

            f32x4 h[2][2];
#pragma unroll
            for (int s = 0; s < 2; s++) {
                f32x4 binit = {b1r[s].x, b1r[s].y, b1r[s].z, b1r[s].w};
#pragma unroll
                for (int mt = 0; mt < 2; mt++) h[s][mt] = binit;
            }
#pragma unroll
            for (int s = 0; s < 2; s++)
#pragma unroll
                for (int ks = 0; ks < 2; ks++)
#pragma unroll
                    for (int mt = 0; mt < 2; mt++)
                        h[s][mt] = __builtin_amdgcn_mfma_f32_16x16x32_bf16(
                            w1r[s][ks], Bt[mt][ks], h[s][mt], 0, 0, 0);

            f16x8 aH[2];
#pragma unroll
            for (int mt = 0; mt < 2; mt++) {
                f16x2 t0 = pk16(fmaxf(h[0][mt][0], 0.f), fmaxf(h[0][mt][1], 0.f));
                f16x2 t1 = pk16(fmaxf(h[0][mt][2], 0.f), fmaxf(h[0][mt][3], 0.f));
                f16x2 t2 = pk16(fmaxf(h[1][mt][0], 0.f), fmaxf(h[1][mt][1], 0.f));
                f16x2 t3 = pk16(fmaxf(h[1][mt][2], 0.f), fmaxf(h[1][mt][3], 0.f));
                f16x8 a;
                a[0] = t0[0]; a[1] = t0[1]; a[2] = t1[0]; a[3] = t1[1];
                a[4] = t2[0]; a[5] = t2[1]; a[6] = t3[0]; a[7] = t3[1];
                aH[mt] = a;
            }

#pragma unroll
            for (int nt = 0; nt < 4; nt++)
#pragma unroll
                for (int mt = 0; mt < 2; mt++)
                    acc[mt][nt] = __builtin_amdgcn_mfma_f32_16x16x32_f16(
                        aH[mt], w2r[nt], acc[mt][nt], 0, 0, 0);
        }
    }

    float b2v[4], gv[4], bev[4];
#pragma unroll
    for (int nt = 0; nt < 4; nt++) {
        b2v[nt] = B2[nt * 16 + lm];
        gv[nt]  = g[nt * 16 + lm];
        bev[nt] = be[nt * 16 + lm];
    }
#pragma unroll
    for (int mt = 0; mt < 2; mt++)
#pragma unroll
        for (int r = 0; r < 4; r++) {
            int row = rowbase + mt * 16 + quad * 4 + r;
            float v[4]; float s = 0.f;
#pragma unroll
            for (int nt = 0; nt < 4; nt++) {
                v[nt] = acc[mt][nt][r] + b2v[nt] +
                        bf2f(T1b[(size_t)row * 64 + nt * 16 + lm]);
                s += v[nt];
            }
#pragma unroll
            for (int o = 8; o; o >>= 1) s += __shfl_xor(s, o, 64);
            float mu = s * 0.015625f;
            float q = 0.f;
#pragma unroll
            for (int nt = 0; nt < 4; nt++) { v[nt] -= mu; q += v[nt] * v[nt]; }
#pragma unroll
            for (int o = 8; o; o >>= 1) q += __shfl_xor(q, o, 64);
            float rstd = rsqrtf(q * 0.015625f + 1e-5f);
#pragma unroll
            for (int nt = 0; nt < 4; nt++)
                OutTb[(size_t)row * 64 + nt * 16 + lm] =
                    f2bf(gv[nt] * v[nt] * rstd + bev[nt]);
        }
}

// ---------------------------------------------------------------------------
// sf2 conv (32->9, MFMA) fused with KPN dynamic filtering.
// ---------------------------------------------------------------------------
__global__ __launch_bounds__(256) void sf2kpn_k(
    const ushort_t* __restrict__ In,
    const ushort_t* __restrict__ Wsw,
    const float* __restrict__ bias,
    const float* __restrict__ x,
    float* __restrict__ fused)
{
    __shared__ float Fl[128 * 12];
    int tid = threadIdx.x, wave = tid >> 6, lane = tid & 63;
    int lm = lane & 15, quad = lane >> 4;
    int m0 = blockIdx.x * 128 + wave * 32;

    int m[2], py[2], px[2];
#pragma unroll
    for (int mt = 0; mt < 2; mt++) {
        int mm = m0 + mt * 16 + lm;
        m[mt] = mm;
        int p = mm - (mm >= HW ? HW : 0);
        py[mt] = p / IW;
        px[mt] = p - py[mt] * IW;
    }

    f32x4 acc[2] = {};
    bf16x8 zz = {};

#pragma unroll 3
    for (int t = 0; t < 9; t++) {
        int dy = t / 3 - 1, dx = t % 3 - 1;
        bf16x8 af[2];
#pragma unroll
        for (int mt = 0; mt < 2; mt++) {
            bool ok = (unsigned)(py[mt] + dy) < (unsigned)IW &&
                      (unsigned)(px[mt] + dx) < (unsigned)IW;
            af[mt] = ok ? ldg8(In + (size_t)(m[mt] + dy * IW + dx) * 32 + quad * 8) : zz;
        }
        bf16x8 bfv = ldg8(Wsw + ((size_t)lm * 9 + t) * 32 + quad * 8);
#pragma unroll
        for (int mt = 0; mt < 2; mt++)
            acc[mt] = __builtin_amdgcn_mfma_f32_16x16x32_bf16(af[mt], bfv, acc[mt], 0, 0, 0);
    }

    if (lm < 9) {
        float bv = bias[lm];
#pragma unroll
        for (int mt = 0; mt < 2; mt++)
#pragma unroll
            for (int r = 0; r < 4; r++) {
                int lrow = wave * 32 + mt * 16 + quad * 4 + r;
                Fl[lrow * 12 + lm] = acc[mt][r] + bv;
            }
    }
    __syncthreads();

    if (tid < 128) {
        int gid = blockIdx.x * 128 + tid;
        int b = gid >= HW;
        int p = gid - b * HW;
        int y = p / IW, xx = p - y * IW;
        const float* fp = &Fl[tid * 12];
        const float* xp = x + (size_t)b * 3 * HW;
        float a = 0.f;
#pragma unroll
        for (int u = 0; u < 3; u++) {
            int yy = y + u - 1;
            if ((unsigned)yy >= (unsigned)IW) continue;
#pragma unroll
            for (int v = 0; v < 3; v++) {
                int xc = xx + v - 1;
                if ((unsigned)xc >= (unsigned)IW) continue;
                int o = yy * IW + xc;
                float s = xp[o] + xp[HW + o] + xp[2 * HW + o];
                a += fp[u * 3 + v] * s;
            }
        }
        fused[gid] = a;
    }
}

// ---------------------------------------------------------------------------
// fused decoder (1 thread/pixel — measured best)
// ---------------------------------------------------------------------------
__global__ __launch_bounds__(256) void dec_fused_k(
    const float* __restrict__ fused,
    const float* __restrict__ w1, const float* __restrict__ b1,
    const float* __restrict__ w2, const float* __restrict__ b2,
    float* __restrict__ out)
{
    int gid = blockIdx.x * 256 + threadIdx.x;
    int b = gid >= HW;
    int p = gid - b * HW;
    int y = p / IW, xx = p - y * IW;
    const float* ip = fused + (size_t)b * HW;

    float F[25];
#pragma unroll
    for (int u = 0; u < 5; u++)
#pragma unroll
        for (int v = 0; v < 5; v++) {
            int yy = y + u - 2, xc = xx + v - 2;
            float t = 0.f;
            if ((unsigned)yy < (unsigned)IW && (unsigned)xc < (unsigned)IW)
                t = ip[yy * IW + xc];
            F[u * 5 + v] = t;
        }
    float nm[9];
#pragma unroll
    for (int n = 0; n < 9; n++) {
        int yy = y + n / 3 - 1, xc = xx + n % 3 - 1;
        nm[n] = ((unsigned)yy < (unsigned)IW && (unsigned)xc < (unsigned)IW) ? 1.f : 0.f;
    }

    float acc = b2[0];
    for (int c = 0; c < 64; c++) {
        float w1c[9], w2c[9];
#pragma unroll
        for (int s = 0; s < 9; s++) { w1c[s] = w1[c * 9 + s]; w2c[s] = w2[c * 9 + s]; }
        float bc = b1[c];
#pragma unroll
        for (int n = 0; n < 9; n++) {
            int ny = n / 3, nx0 = n % 3;
            float h = bc;
#pragma unroll
            for (int s = 0; s < 9; s++)
                h = fmaf(F[(ny + s / 3) * 5 + (nx0 + s % 3)], w1c[s], h);
            acc = fmaf(fmaxf(h, 0.f), w2c[n] * nm[n], acc);
        }
    }
    out[gid] = 1.f / (1.f + __expf(-acc));
}

// ---------------------------------------------------------------------------
extern "C" void kernel_launch(void* const* d_in, const int* in_sizes, int n_in,
                              void* d_out, int out_size, void* d_ws, size_t ws_size,
                              hipStream_t stream)
{
    const float* x      = (const float*)d_in[0];
    const float* enc_w1 = (const float*)d_in[1];
    const float* enc_b1 = (const float*)d_in[2];
    const float* enc_w2 = (const float*)d_in[3];
    const float* enc_b2 = (const float*)d_in[4];
    const float* in_w   = (const float*)d_in[5];
    const float* in_b   = (const float*)d_in[6];
    const float* out_w  = (const float*)d_in[7];
    const float* out_b  = (const float*)d_in[8];
    const float* ln1_g  = (const float*)d_in[9];
    const float* ln1_b  = (const float*)d_in[10];
    const float* ffn_w1 = (const float*)d_in[11];
    const float* ffn_b1 = (const float*)d_in[12];
    const float* ffn_w2 = (const float*)d_in[13];
    const float* ffn_b2 = (const float*)d_in[14];
    const float* ln2_g  = (const float*)d_in[15];
    const float* ln2_b  = (const float*)d_in[16];
    const float* sf_w1  = (const float*)d_in[17];
    const float* sf_b1  = (const float*)d_in[18];
    const float* sf_w2  = (const float*)d_in[19];
    const float* sf_b2  = (const float*)d_in[20];
    const float* dec_w1 = (const float*)d_in[21];
    const float* dec_b1 = (const float*)d_in[22];
    const float* dec_w2 = (const float*)d_in[23];
    const float* dec_b2 = (const float*)d_in[24];

    float* ws = (float*)d_ws;
    const size_t SZ = (size_t)NPIX * 64;

    ushort_t* E1b  = (ushort_t*)(ws + 5 * SZ);             // conv1 out / t2 bf16
    ushort_t* Tb   = (ushort_t*)(ws + 11 * SZ / 2);        // t1 bf16
    ushort_t* wu   = (ushort_t*)(ws + 6 * SZ);             // weights
    ushort_t* in_wb  = wu;                                 // 12288
    ushort_t* out_wb = wu + 12288;                         // 4096
    ushort_t* w1p    = wu + 16384;                         // 196608 (padded chunks)
    _Float16* w2s    = (_Float16*)(wu + 212992);           // 131072 halves
    ushort_t* wc2p   = wu + 344064;                        // 41472 (tap-major padded)
    ushort_t* ws1p   = wu + 385536;                        // 23040 (tap-major padded)
    ushort_t* ws2    = wu + 408576;                        // 4608
    // late-stage scratch:
    float*    base3 = ws + 3 * SZ;
    ushort_t* s1b   = (ushort_t*)base3;                    // NPIX*32 bf16
    float*    fused = base3 + SZ / 2;                      // NPIX

    // ---- merged weight prep + conv1 ----
    prep_conv1_k<<<1714, 256, 0, stream>>>(
        x, enc_w1, enc_b1, E1b,
        in_w, in_wb, out_w, out_wb, ffn_w1, w1p,
        ffn_w2, w2s, enc_w2, wc2p, sf_w1, ws1p, sf_w2, ws2);

    // ---- fused enc-conv2 + transformer front -> t1 (Tb) ----
    enc2xf_k<<<784, 256, 0, stream>>>(E1b, wc2p, enc_b2,
                                      in_wb, in_b, out_wb, out_b,
                                      ln1_g, ln1_b, Tb);
    // ---- FFN (+res+LN2) -> t2 (E1b, dead after enc2xf) ----
    ffn8_k<<<392, 512, 0, stream>>>(Tb, w1p, ffn_b1, w2s, ffn_b2, ln2_g, ln2_b, E1b);
    // ---- filter prediction ----
    neconv_lds_k<2, 2, 2560, 5, 0, false, true><<<784, 256, 0, stream>>>(
        E1b, ws1p, sf_b1, nullptr, s1b);
    // ---- sf2 conv + KPN fused ----
    sf2kpn_k<<<784, 256, 0, stream>>>(s1b, ws2, sf_b2, x, fused);
    // ---- fused decoder ----
    dec_fused_k<<<392, 256, 0, stream>>>(fused, dec_w1, dec_b1, dec_w2, dec_b2,
                                         (float*)d_out);
}